// Round 8
// baseline (155.101 us; speedup 1.0000x reference)
//
#include <hip/hip_runtime.h>
#include <math.h>

#define B_   128
#define T_   1024
#define D_   256
#define L_   512

__device__ __forceinline__ float sigmoidf_(float x) {
    return 1.f / (1.f + __expf(-x));
}
__device__ __forceinline__ float tanhf_(float x) {
    x = fminf(fmaxf(x, -15.f), 15.f);
    float e = __expf(2.f * x);
    return (e - 1.f) / (e + 1.f);
}
// tanh(x) = 1 - 2/(exp(2x)+1); exact identity, v_exp + v_rcp
__device__ __forceinline__ float tanh_fast(float x) {
    float e = __expf(2.f * x);
    return 1.f - 2.f * __builtin_amdgcn_rcpf(e + 1.f);
}
__device__ __forceinline__ float waveReduceSum(float v) {
    #pragma unroll
    for (int o = 32; o > 0; o >>= 1) v += __shfl_xor(v, o, 64);
    return v;
}

// ---------------------------------------------------------------------------
// K1a: prenet per batch.  grid=128, block=256
// ---------------------------------------------------------------------------
__global__ __launch_bounds__(256) void k1a_prenet(
    const float* __restrict__ prenet_in,
    const float* __restrict__ fc1_W, const float* __restrict__ fc1_b,
    const float* __restrict__ fc2_W, const float* __restrict__ fc2_b,
    float* __restrict__ p2_out)
{
    const int b = blockIdx.x, t = threadIdx.x;
    __shared__ __align__(16) float pin[80];
    __shared__ __align__(16) float p1[256];

    if (t < 80) pin[t] = prenet_in[b * 80 + t];
    __syncthreads();

    {
        float a = fc1_b[t];
        const float4* w  = (const float4*)(fc1_W + t * 80);
        const float4* xv = (const float4*)pin;
        #pragma unroll
        for (int k = 0; k < 20; k++) {
            float4 wv = w[k], v = xv[k];
            a += v.x * wv.x + v.y * wv.y + v.z * wv.z + v.w * wv.w;
        }
        p1[t] = fmaxf(a, 0.f);
    }
    __syncthreads();

    if (t < 128) {
        float a = fc2_b[t];
        const float4* w  = (const float4*)(fc2_W + t * 256);
        const float4* xv = (const float4*)p1;
        #pragma unroll 8
        for (int k = 0; k < 64; k++) {
            float4 wv = w[k], v = xv[k];
            a += v.x * wv.x + v.y * wv.y + v.z * wv.z + v.w * wv.w;
        }
        p2_out[b * 128 + t] = fmaxf(a, 0.f);
    }
}

// ---------------------------------------------------------------------------
// K1b: GRU gate GEMVs.  grid = (3 j-tiles, 64 batch-pairs), block = 256.
// ---------------------------------------------------------------------------
__global__ __launch_bounds__(256) void k1b_gru_gemv(
    const float* __restrict__ context_vec, const float* __restrict__ p2,
    const float* __restrict__ attn_hidden,
    const float* __restrict__ gru_Wih, const float* __restrict__ gru_Whh,
    const float* __restrict__ gru_bih, const float* __restrict__ gru_bhh,
    float* __restrict__ gi_out, float* __restrict__ gh_out)
{
    const int t = threadIdx.x;
    const int j = blockIdx.x * 256 + t;
    const int b0 = blockIdx.y * 2;

    __shared__ __align__(16) float xs[2][384];
    __shared__ __align__(16) float hs[2][256];

    for (int i = t; i < 768; i += 256) {
        int bb = i / 384, k = i % 384;
        xs[bb][k] = (k < 256) ? context_vec[(b0 + bb) * 256 + k]
                              : p2[(b0 + bb) * 128 + (k - 256)];
    }
    for (int i = t; i < 512; i += 256) {
        hs[i / 256][i % 256] = attn_hidden[(b0 + i / 256) * 256 + (i % 256)];
    }
    __syncthreads();

    {
        float a0 = gru_bih[j], a1 = a0;
        const float4* w  = (const float4*)(gru_Wih + (size_t)j * 384);
        const float4* x0 = (const float4*)xs[0];
        const float4* x1 = (const float4*)xs[1];
        #pragma unroll 8
        for (int k = 0; k < 96; k++) {
            float4 wv = w[k], v0 = x0[k], v1 = x1[k];
            a0 += v0.x * wv.x + v0.y * wv.y + v0.z * wv.z + v0.w * wv.w;
            a1 += v1.x * wv.x + v1.y * wv.y + v1.z * wv.z + v1.w * wv.w;
        }
        gi_out[(size_t)(b0 + 0) * 768 + j] = a0;
        gi_out[(size_t)(b0 + 1) * 768 + j] = a1;
    }
    {
        float a0 = gru_bhh[j], a1 = a0;
        const float4* w  = (const float4*)(gru_Whh + (size_t)j * 256);
        const float4* x0 = (const float4*)hs[0];
        const float4* x1 = (const float4*)hs[1];
        #pragma unroll 8
        for (int k = 0; k < 64; k++) {
            float4 wv = w[k], v0 = x0[k], v1 = x1[k];
            a0 += v0.x * wv.x + v0.y * wv.y + v0.z * wv.z + v0.w * wv.w;
            a1 += v1.x * wv.x + v1.y * wv.y + v1.z * wv.z + v1.w * wv.w;
        }
        gh_out[(size_t)(b0 + 0) * 768 + j] = a0;
        gh_out[(size_t)(b0 + 1) * 768 + j] = a1;
    }
}

// ---------------------------------------------------------------------------
// K1c: GRU gates + q = attn_h @ attn_W.T.   grid=128, block=256
// ---------------------------------------------------------------------------
__global__ __launch_bounds__(256) void k1c_gates_q(
    const float* __restrict__ gi, const float* __restrict__ gh,
    const float* __restrict__ attn_hidden, const float* __restrict__ attn_W,
    float* __restrict__ attn_h_out, float* __restrict__ q_out)
{
    const int b = blockIdx.x, t = threadIdx.x;
    __shared__ __align__(16) float ahn[256];

    {
        float hp = attn_hidden[b * 256 + t];
        float rg = sigmoidf_(gi[(size_t)b * 768 + t]       + gh[(size_t)b * 768 + t]);
        float zg = sigmoidf_(gi[(size_t)b * 768 + 256 + t] + gh[(size_t)b * 768 + 256 + t]);
        float ng = tanhf_(gi[(size_t)b * 768 + 512 + t] + rg * gh[(size_t)b * 768 + 512 + t]);
        float h  = (1.f - zg) * ng + zg * hp;
        ahn[t] = h;
        attn_h_out[b * 256 + t] = h;
    }
    __syncthreads();

    {
        float a = 0.f;
        const float4* w  = (const float4*)(attn_W + (size_t)t * 256);
        const float4* xv = (const float4*)ahn;
        #pragma unroll 8
        for (int k = 0; k < 64; k++) {
            float4 wv = w[k], v = xv[k];
            a += v.x * wv.x + v.y * wv.y + v.z * wv.z + v.w * wv.w;
        }
        q_out[b * 256 + t] = a;
    }
}

// ---------------------------------------------------------------------------
// KU: u-pass (pure encp stream).  grid = B*8 = 1024, block = 256 (4 waves).
// Wave wv owns 32 rows (slab of 128 rows per block).  Per row: one coalesced
// 1KB wave load, per-lane column partial -> private LDS slab.  In-wave LDS
// reduce (2 lanes/row, shfl_xor(1) combine).  NO __syncthreads anywhere.
// e=exp(u) deferred to KC (no softmax max: |u|<=sum|v|~10, fp32-safe).
// ---------------------------------------------------------------------------
__global__ __launch_bounds__(256, 4) void ku_scores(
    const float* __restrict__ enc_proj, const float* __restrict__ q,
    const float* __restrict__ v, float* __restrict__ u_out)
{
    const int b    = blockIdx.x >> 3;
    const int slab = blockIdx.x & 7;
    const int tid  = threadIdx.x;
    const int wv   = tid >> 6, lane = tid & 63;
    const int t0w  = slab * 128 + wv * 32;       // wave's 32 rows

    __shared__ float lds_p[4][32][65];           // 33.3 KB, per-wave slabs

    const float4 q4 = ((const float4*)(q + b * 256))[lane];
    const float4 v4 = ((const float4*)v)[lane];

    const float4* prow = (const float4*)(enc_proj + ((size_t)(b * T_ + t0w)) * 256);
    #pragma unroll 8
    for (int r = 0; r < 32; r++) {
        float4 p = prow[(size_t)r * 64 + lane];
        lds_p[wv][r][lane] = tanh_fast(p.x + q4.x) * v4.x
                           + tanh_fast(p.y + q4.y) * v4.y
                           + tanh_fast(p.z + q4.z) * v4.z
                           + tanh_fast(p.w + q4.w) * v4.w;
    }

    // in-wave reduce: 2 lanes per row, each sums 32 entries
    const int row = lane >> 1, half = lane & 1;
    float u0 = 0.f, u1 = 0.f, u2 = 0.f, u3 = 0.f;
    #pragma unroll
    for (int j = 0; j < 32; j += 4) {
        u0 += lds_p[wv][row][half * 32 + j + 0];
        u1 += lds_p[wv][row][half * 32 + j + 1];
        u2 += lds_p[wv][row][half * 32 + j + 2];
        u3 += lds_p[wv][row][half * 32 + j + 3];
    }
    float us = (u0 + u1) + (u2 + u3);
    us += __shfl_xor(us, 1, 64);
    if (half == 0) u_out[b * T_ + t0w + row] = us;
}

// ---------------------------------------------------------------------------
// KC: context pass (pure enc stream).  grid = B*16 = 2048, block = 256.
// Wave wv owns 16 rows of the 64-row chunk: e[16] in registers (uniform u
// loads, exp), 16 coalesced 1KB loads, register float4 acc.  One barrier.
// ---------------------------------------------------------------------------
__global__ __launch_bounds__(256, 4) void kc_context(
    const float* __restrict__ enc, const float* __restrict__ u_in,
    float* __restrict__ ctx_part, float* __restrict__ s_part)
{
    const int b     = blockIdx.x >> 4;
    const int chunk = blockIdx.x & 15;
    const int tid   = threadIdx.x;
    const int wv    = tid >> 6, lane = tid & 63;
    const int t0    = chunk * 64;

    __shared__ __align__(16) float4 red[3][64];
    __shared__ float sred[4];

    // per-wave e values (uniform across lanes; L1 broadcast)
    const float* ub = u_in + b * T_ + t0 + wv * 16;
    float e[16];
    float ssum = 0.f;
    #pragma unroll
    for (int j = 0; j < 16; j++) { e[j] = __expf(ub[j]); ssum += e[j]; }
    if (lane == 0) sred[wv] = ssum;

    const float4* erow = (const float4*)(enc + ((size_t)(b * T_ + t0 + wv * 16)) * 256);
    float4 accA = {0.f, 0.f, 0.f, 0.f}, accB = {0.f, 0.f, 0.f, 0.f};
    #pragma unroll
    for (int j = 0; j < 16; j += 2) {
        float4 r0 = erow[(size_t)(j + 0) * 64 + lane];
        float4 r1 = erow[(size_t)(j + 1) * 64 + lane];
        accA.x += e[j] * r0.x;     accA.y += e[j] * r0.y;
        accA.z += e[j] * r0.z;     accA.w += e[j] * r0.w;
        accB.x += e[j + 1] * r1.x; accB.y += e[j + 1] * r1.y;
        accB.z += e[j + 1] * r1.z; accB.w += e[j + 1] * r1.w;
    }
    accA.x += accB.x; accA.y += accB.y; accA.z += accB.z; accA.w += accB.w;

    if (wv) red[wv - 1][lane] = accA;
    __syncthreads();
    if (wv == 0) {
        float4 a1 = red[0][lane], a2 = red[1][lane], a3 = red[2][lane];
        accA.x += a1.x + a2.x + a3.x;
        accA.y += a1.y + a2.y + a3.y;
        accA.z += a1.z + a2.z + a3.z;
        accA.w += a1.w + a2.w + a3.w;
        ((float4*)ctx_part)[(size_t)(b * 16 + chunk) * 64 + lane] = accA;
        if (lane == 0)
            s_part[b * 16 + chunk] = sred[0] + sred[1] + sred[2] + sred[3];
    }
}

// ---------------------------------------------------------------------------
// KB: combine 16 partials -> context, scores, concat1.  grid=128 (per batch)
// ---------------------------------------------------------------------------
__global__ __launch_bounds__(256) void kb_combine(
    const float* __restrict__ u, const float* __restrict__ s_part,
    const float* __restrict__ ctx_part, const float* __restrict__ attn_h,
    float* __restrict__ scores_out, float* __restrict__ ctx_out,
    float* __restrict__ concat1)
{
    const int b = blockIdx.x, tid = threadIdx.x;
    __shared__ float ssh[16];
    if (tid < 16) ssh[tid] = s_part[b * 16 + tid];
    __syncthreads();

    float S = 0.f;
    #pragma unroll
    for (int c = 0; c < 16; c++) S += ssh[c];
    float invS = 1.f / S;

    {
        float a = 0.f;
        #pragma unroll
        for (int c = 0; c < 16; c++)
            a += ctx_part[(size_t)(b * 16 + c) * 256 + tid];
        a *= invS;
        ctx_out[b * 256 + tid] = a;
        concat1[b * 512 + tid] = a;
        concat1[b * 512 + 256 + tid] = attn_h[b * 256 + tid];
    }

    #pragma unroll
    for (int i = 0; i < 4; i++) {
        int t = i * 256 + tid;
        scores_out[b * T_ + t] = __expf(u[b * T_ + t]) * invS;
    }
}

// ---------------------------------------------------------------------------
// GEMM: part[z][m][n] = A_seg[m][k0:k0+KSZ] @ W_seg[n][k0:k0+KSZ]^T
// ---------------------------------------------------------------------------
__global__ __launch_bounds__(256) void gemm512_splitk(
    const float* __restrict__ A1, const float* __restrict__ W1,
    const float* __restrict__ A2, const float* __restrict__ W2,
    float* __restrict__ part, int N, int ksPerSeg)
{
    const int n0 = blockIdx.x * 64, m0 = blockIdx.y * 64;
    const int seg = blockIdx.z / ksPerSeg, ls = blockIdx.z % ksPerSeg;
    const int KSZ = 512 / ksPerSeg;
    const float* A = seg ? A2 : A1;
    const float* W = seg ? W2 : W1;
    const int k0 = ls * KSZ;

    __shared__ __align__(16) float As[32][68];
    __shared__ __align__(16) float Ws[32][68];

    const int tid = threadIdx.x;
    const int tm = tid & 15, tn = tid >> 4;
    const int rs = tid >> 3, qs = tid & 7;

    float acc[4][4] = {};

    for (int kt = 0; kt < KSZ; kt += 32) {
        #pragma unroll
        for (int it = 0; it < 2; it++) {
            int r = rs + it * 32;
            float4 av = *(const float4*)(A + (size_t)(m0 + r) * 512 + k0 + kt + qs * 4);
            As[qs * 4 + 0][r] = av.x; As[qs * 4 + 1][r] = av.y;
            As[qs * 4 + 2][r] = av.z; As[qs * 4 + 3][r] = av.w;
            float4 wv = *(const float4*)(W + (size_t)(n0 + r) * 512 + k0 + kt + qs * 4);
            Ws[qs * 4 + 0][r] = wv.x; Ws[qs * 4 + 1][r] = wv.y;
            Ws[qs * 4 + 2][r] = wv.z; Ws[qs * 4 + 3][r] = wv.w;
        }
        __syncthreads();
        #pragma unroll
        for (int kk = 0; kk < 32; kk++) {
            float4 a = *(const float4*)&As[kk][tm * 4];
            float4 w = *(const float4*)&Ws[kk][tn * 4];
            acc[0][0] += a.x * w.x; acc[0][1] += a.x * w.y; acc[0][2] += a.x * w.z; acc[0][3] += a.x * w.w;
            acc[1][0] += a.y * w.x; acc[1][1] += a.y * w.y; acc[1][2] += a.y * w.z; acc[1][3] += a.y * w.w;
            acc[2][0] += a.z * w.x; acc[2][1] += a.z * w.y; acc[2][2] += a.z * w.z; acc[2][3] += a.z * w.w;
            acc[3][0] += a.w * w.x; acc[3][1] += a.w * w.y; acc[3][2] += a.w * w.z; acc[3][3] += a.w * w.w;
        }
        __syncthreads();
    }

    float* pb = part + ((size_t)blockIdx.z * 128 + m0) * N + n0;
    #pragma unroll
    for (int i = 0; i < 4; i++) {
        float4 o = {acc[i][0], acc[i][1], acc[i][2], acc[i][3]};
        *(float4*)(pb + (size_t)(tm * 4 + i) * N + tn * 4) = o;
    }
}

// ---------------------------------------------------------------------------
// E_rnn: x = sum_z part[z] + bias     (N=512, 16 slices)
// ---------------------------------------------------------------------------
__global__ __launch_bounds__(256) void e_rnn(
    const float* __restrict__ part, const float* __restrict__ bias,
    float* __restrict__ x)
{
    const int idx = blockIdx.x * 256 + threadIdx.x;
    const int n = idx & 511;
    float a = bias[n];
    #pragma unroll
    for (int z = 0; z < 16; z++) a += part[(size_t)z * 65536 + idx];
    x[idx] = a;
}

// ---------------------------------------------------------------------------
__global__ __launch_bounds__(256) void e_lstm(
    const float* __restrict__ part,
    const float* __restrict__ bih, const float* __restrict__ bhh,
    const float* __restrict__ c_prev, const float* __restrict__ x_prev,
    float* __restrict__ h_out, float* __restrict__ c_out, float* __restrict__ x_new)
{
    const int idx = blockIdx.x * 256 + threadIdx.x;
    const int bb = idx >> 9, j = idx & 511;
    float gi = bih[j] + bhh[j];
    float gf = bih[512 + j] + bhh[512 + j];
    float gg = bih[1024 + j] + bhh[1024 + j];
    float go = bih[1536 + j] + bhh[1536 + j];
    #pragma unroll
    for (int z = 0; z < 4; z++) {
        const float* p = part + ((size_t)z * 128 + bb) * 2048;
        gi += p[j]; gf += p[512 + j]; gg += p[1024 + j]; go += p[1536 + j];
    }
    float c = sigmoidf_(gf) * c_prev[idx] + sigmoidf_(gi) * tanhf_(gg);
    float h = sigmoidf_(go) * tanhf_(c);
    h_out[idx] = h;
    c_out[idx] = c;
    x_new[idx] = x_prev[idx] + h;
}

// ---------------------------------------------------------------------------
__global__ __launch_bounds__(512) void e_lstm2_mel(
    const float* __restrict__ part,
    const float* __restrict__ bih, const float* __restrict__ bhh,
    const float* __restrict__ c_prev, const float* __restrict__ x_prev,
    const float* __restrict__ mel_W, const int* __restrict__ r_ptr,
    float* __restrict__ h_out, float* __restrict__ c_out,
    float* __restrict__ mels)
{
    const int b = blockIdx.x, j = threadIdx.x;
    __shared__ __align__(16) float xs[512];

    const int idx = b * 512 + j;
    float gi = bih[j] + bhh[j];
    float gf = bih[512 + j] + bhh[512 + j];
    float gg = bih[1024 + j] + bhh[1024 + j];
    float go = bih[1536 + j] + bhh[1536 + j];
    #pragma unroll
    for (int z = 0; z < 4; z++) {
        const float* p = part + ((size_t)z * 128 + b) * 2048;
        gi += p[j]; gf += p[512 + j]; gg += p[1024 + j]; go += p[1536 + j];
    }
    float c = sigmoidf_(gf) * c_prev[idx] + sigmoidf_(gi) * tanhf_(gg);
    float h = sigmoidf_(go) * tanhf_(c);
    h_out[idx] = h;
    c_out[idx] = c;
    xs[j] = x_prev[idx] + h;
    __syncthreads();

    const int r = r_ptr[0];
    const int tot = 80 * r;
    for (int n = j; n < tot; n += 512) {
        int m = n / r, rr = n % r;
        const float4* w  = (const float4*)(mel_W + (size_t)(m * 20 + rr) * 512);
        const float4* xv = (const float4*)xs;
        float a = 0.f;
        #pragma unroll 8
        for (int k = 0; k < 128; k++) {
            float4 wv = w[k], vv = xv[k];
            a += wv.x * vv.x + wv.y * vv.y + wv.z * vv.z + wv.w * vv.w;
        }
        mels[(size_t)b * tot + n] = a;
    }
}

// ---------------------------------------------------------------------------
extern "C" void kernel_launch(void* const* d_in, const int* in_sizes, int n_in,
                              void* d_out, int out_size, void* d_ws, size_t ws_size,
                              hipStream_t stream)
{
    const float* enc   = (const float*)d_in[0];
    const float* encp  = (const float*)d_in[1];
    const float* pre   = (const float*)d_in[2];
    const float* ah_in = (const float*)d_in[3];
    const float* r1h   = (const float*)d_in[4];
    const float* r2h   = (const float*)d_in[5];
    const float* r1c   = (const float*)d_in[6];
    const float* r2c   = (const float*)d_in[7];
    const float* cvec  = (const float*)d_in[8];
    const float* fc1W  = (const float*)d_in[9];
    const float* fc1b  = (const float*)d_in[10];
    const float* fc2W  = (const float*)d_in[11];
    const float* fc2b  = (const float*)d_in[12];
    const float* attnW = (const float*)d_in[13];
    const float* attnv = (const float*)d_in[14];
    const float* gWih  = (const float*)d_in[15];
    const float* gWhh  = (const float*)d_in[16];
    const float* gbih  = (const float*)d_in[17];
    const float* gbhh  = (const float*)d_in[18];
    const float* rinW  = (const float*)d_in[19];
    const float* rinb  = (const float*)d_in[20];
    const float* l1Wih = (const float*)d_in[21];
    const float* l1Whh = (const float*)d_in[22];
    const float* l1bih = (const float*)d_in[23];
    const float* l1bhh = (const float*)d_in[24];
    const float* l2Wih = (const float*)d_in[25];
    const float* l2Whh = (const float*)d_in[26];
    const float* l2bih = (const float*)d_in[27];
    const float* l2bhh = (const float*)d_in[28];
    const float* melW  = (const float*)d_in[29];
    const int*   rp    = (const int*)d_in[30];

    float* out = (float*)d_out;
    float* o_mels  = out + 0;        // 128*80*2
    float* o_scor  = out + 20480;    // 128*1024
    float* o_attnh = out + 151552;   // 128*256
    float* o_r1h   = out + 184320;   // 128*512
    float* o_r2h   = out + 249856;
    float* o_r1c   = out + 315392;
    float* o_r2c   = out + 380928;
    float* o_ctx   = out + 446464;   // 128*256

    float* ws     = (float*)d_ws;
    float* w_q    = ws + 0;          // 32768
    float* w_u    = ws + 32768;      // 131072
    float* w_s    = ws + 163840;     // 2048
    float* w_ctxp = ws + 165888;     // 16*128*256 = 524288
    float* w_cat1 = ws + 692224;     // 65536
    float* w_x    = ws + 757760;     // 65536
    float* w_x2   = ws + 823296;     // 65536
    float* w_part = ws + 888832;     // 16*128*512 = 1048576 max

    // front-end scratch reuses the w_part region (free until the GEMM phase)
    float* w_p2 = w_part;            // 128*128
    float* w_gi = w_part + 16384;    // 128*768
    float* w_gh = w_part + 114688;   // 128*768

    hipLaunchKernelGGL(k1a_prenet, dim3(128), dim3(256), 0, stream,
                       pre, fc1W, fc1b, fc2W, fc2b, w_p2);

    hipLaunchKernelGGL(k1b_gru_gemv, dim3(3, 64), dim3(256), 0, stream,
                       cvec, w_p2, ah_in, gWih, gWhh, gbih, gbhh, w_gi, w_gh);

    hipLaunchKernelGGL(k1c_gates_q, dim3(128), dim3(256), 0, stream,
                       w_gi, w_gh, ah_in, attnW, o_attnh, w_q);

    hipLaunchKernelGGL(ku_scores, dim3(1024), dim3(256), 0, stream,
                       encp, w_q, attnv, w_u);

    hipLaunchKernelGGL(kc_context, dim3(2048), dim3(256), 0, stream,
                       enc, w_u, w_ctxp, w_s);

    hipLaunchKernelGGL(kb_combine, dim3(128), dim3(256), 0, stream,
                       w_u, w_s, w_ctxp, o_attnh, o_scor, o_ctx, w_cat1);

    // rnn_in: K=512, 16 k-slices -> 256 blocks
    hipLaunchKernelGGL(gemm512_splitk, dim3(8, 2, 16), dim3(256), 0, stream,
                       w_cat1, rinW, w_cat1, rinW, w_part, 512, 16);
    hipLaunchKernelGGL(e_rnn, dim3(256), dim3(256), 0, stream, w_part, rinb, w_x);

    // LSTM 1
    hipLaunchKernelGGL(gemm512_splitk, dim3(32, 2, 4), dim3(256), 0, stream,
                       w_x, l1Wih, r1h, l1Whh, w_part, 2048, 2);
    hipLaunchKernelGGL(e_lstm, dim3(256), dim3(256), 0, stream,
                       w_part, l1bih, l1bhh, r1c, w_x, o_r1h, o_r1c, w_x2);

    // LSTM 2 + mel
    hipLaunchKernelGGL(gemm512_splitk, dim3(32, 2, 4), dim3(256), 0, stream,
                       w_x2, l2Wih, r2h, l2Whh, w_part, 2048, 2);
    hipLaunchKernelGGL(e_lstm2_mel, dim3(128), dim3(512), 0, stream,
                       w_part, l2bih, l2bhh, r2c, w_x2, melW, rp,
                       o_r2h, o_r2c, o_mels);
}

// Round 9
// 145.919 us; speedup vs baseline: 1.0629x; 1.0629x over previous
//
#include <hip/hip_runtime.h>
#include <math.h>

#define B_   128
#define T_   1024
#define D_   256
#define L_   512

__device__ __forceinline__ float sigmoidf_(float x) {
    return 1.f / (1.f + __expf(-x));
}
__device__ __forceinline__ float tanhf_(float x) {
    x = fminf(fmaxf(x, -15.f), 15.f);
    float e = __expf(2.f * x);
    return (e - 1.f) / (e + 1.f);
}
// tanh(x) = 1 - 2/(exp(2x)+1); exact identity, v_exp + v_rcp
__device__ __forceinline__ float tanh_fast(float x) {
    float e = __expf(2.f * x);
    return 1.f - 2.f * __builtin_amdgcn_rcpf(e + 1.f);
}
__device__ __forceinline__ float waveReduceSum(float v) {
    #pragma unroll
    for (int o = 32; o > 0; o >>= 1) v += __shfl_xor(v, o, 64);
    return v;
}

// non-temporal float4 load (streams bypass L3 allocation)
typedef float f4v __attribute__((ext_vector_type(4)));
__device__ __forceinline__ float4 nt_load4(const float4* p) {
    f4v v = __builtin_nontemporal_load((const f4v*)p);
    return make_float4(v.x, v.y, v.z, v.w);
}

// ---------------------------------------------------------------------------
// K1a: prenet per batch.  grid=128, block=256
// ---------------------------------------------------------------------------
__global__ __launch_bounds__(256) void k1a_prenet(
    const float* __restrict__ prenet_in,
    const float* __restrict__ fc1_W, const float* __restrict__ fc1_b,
    const float* __restrict__ fc2_W, const float* __restrict__ fc2_b,
    float* __restrict__ p2_out)
{
    const int b = blockIdx.x, t = threadIdx.x;
    __shared__ __align__(16) float pin[80];
    __shared__ __align__(16) float p1[256];

    if (t < 80) pin[t] = prenet_in[b * 80 + t];
    __syncthreads();

    {
        float a = fc1_b[t];
        const float4* w  = (const float4*)(fc1_W + t * 80);
        const float4* xv = (const float4*)pin;
        #pragma unroll
        for (int k = 0; k < 20; k++) {
            float4 wv = w[k], v = xv[k];
            a += v.x * wv.x + v.y * wv.y + v.z * wv.z + v.w * wv.w;
        }
        p1[t] = fmaxf(a, 0.f);
    }
    __syncthreads();

    if (t < 128) {
        float a = fc2_b[t];
        const float4* w  = (const float4*)(fc2_W + t * 256);
        const float4* xv = (const float4*)p1;
        #pragma unroll 8
        for (int k = 0; k < 64; k++) {
            float4 wv = w[k], v = xv[k];
            a += v.x * wv.x + v.y * wv.y + v.z * wv.z + v.w * wv.w;
        }
        p2_out[b * 128 + t] = fmaxf(a, 0.f);
    }
}

// ---------------------------------------------------------------------------
// K1b: GRU gate GEMVs.  grid = (3 j-tiles, 64 batch-pairs), block = 256.
// ---------------------------------------------------------------------------
__global__ __launch_bounds__(256) void k1b_gru_gemv(
    const float* __restrict__ context_vec, const float* __restrict__ p2,
    const float* __restrict__ attn_hidden,
    const float* __restrict__ gru_Wih, const float* __restrict__ gru_Whh,
    const float* __restrict__ gru_bih, const float* __restrict__ gru_bhh,
    float* __restrict__ gi_out, float* __restrict__ gh_out)
{
    const int t = threadIdx.x;
    const int j = blockIdx.x * 256 + t;
    const int b0 = blockIdx.y * 2;

    __shared__ __align__(16) float xs[2][384];
    __shared__ __align__(16) float hs[2][256];

    for (int i = t; i < 768; i += 256) {
        int bb = i / 384, k = i % 384;
        xs[bb][k] = (k < 256) ? context_vec[(b0 + bb) * 256 + k]
                              : p2[(b0 + bb) * 128 + (k - 256)];
    }
    for (int i = t; i < 512; i += 256) {
        hs[i / 256][i % 256] = attn_hidden[(b0 + i / 256) * 256 + (i % 256)];
    }
    __syncthreads();

    {
        float a0 = gru_bih[j], a1 = a0;
        const float4* w  = (const float4*)(gru_Wih + (size_t)j * 384);
        const float4* x0 = (const float4*)xs[0];
        const float4* x1 = (const float4*)xs[1];
        #pragma unroll 8
        for (int k = 0; k < 96; k++) {
            float4 wv = w[k], v0 = x0[k], v1 = x1[k];
            a0 += v0.x * wv.x + v0.y * wv.y + v0.z * wv.z + v0.w * wv.w;
            a1 += v1.x * wv.x + v1.y * wv.y + v1.z * wv.z + v1.w * wv.w;
        }
        gi_out[(size_t)(b0 + 0) * 768 + j] = a0;
        gi_out[(size_t)(b0 + 1) * 768 + j] = a1;
    }
    {
        float a0 = gru_bhh[j], a1 = a0;
        const float4* w  = (const float4*)(gru_Whh + (size_t)j * 256);
        const float4* x0 = (const float4*)hs[0];
        const float4* x1 = (const float4*)hs[1];
        #pragma unroll 8
        for (int k = 0; k < 64; k++) {
            float4 wv = w[k], v0 = x0[k], v1 = x1[k];
            a0 += v0.x * wv.x + v0.y * wv.y + v0.z * wv.z + v0.w * wv.w;
            a1 += v1.x * wv.x + v1.y * wv.y + v1.z * wv.z + v1.w * wv.w;
        }
        gh_out[(size_t)(b0 + 0) * 768 + j] = a0;
        gh_out[(size_t)(b0 + 1) * 768 + j] = a1;
    }
}

// ---------------------------------------------------------------------------
// K1c: GRU gates + q = attn_h @ attn_W.T.   grid=128, block=256
// ---------------------------------------------------------------------------
__global__ __launch_bounds__(256) void k1c_gates_q(
    const float* __restrict__ gi, const float* __restrict__ gh,
    const float* __restrict__ attn_hidden, const float* __restrict__ attn_W,
    float* __restrict__ attn_h_out, float* __restrict__ q_out)
{
    const int b = blockIdx.x, t = threadIdx.x;
    __shared__ __align__(16) float ahn[256];

    {
        float hp = attn_hidden[b * 256 + t];
        float rg = sigmoidf_(gi[(size_t)b * 768 + t]       + gh[(size_t)b * 768 + t]);
        float zg = sigmoidf_(gi[(size_t)b * 768 + 256 + t] + gh[(size_t)b * 768 + 256 + t]);
        float ng = tanhf_(gi[(size_t)b * 768 + 512 + t] + rg * gh[(size_t)b * 768 + 512 + t]);
        float h  = (1.f - zg) * ng + zg * hp;
        ahn[t] = h;
        attn_h_out[b * 256 + t] = h;
    }
    __syncthreads();

    {
        float a = 0.f;
        const float4* w  = (const float4*)(attn_W + (size_t)t * 256);
        const float4* xv = (const float4*)ahn;
        #pragma unroll 8
        for (int k = 0; k < 64; k++) {
            float4 wv = w[k], v = xv[k];
            a += v.x * wv.x + v.y * wv.y + v.z * wv.z + v.w * wv.w;
        }
        q_out[b * 256 + t] = a;
    }
}

// ---------------------------------------------------------------------------
// KA (R6 structure + NON-TEMPORAL streams): 1 wave per 64-row chunk.
//  stage1: lane owns row, u fully in-lane, 16 independent nt loads.
//  stage2: e=exp(u) (no max; |u|<=sum|v|~10, fp32-safe, shift-invariant).
//  stage3: 64 contiguous enc rows via nt loads, per-lane float4 acc.
// ---------------------------------------------------------------------------
__global__ __launch_bounds__(64, 2) void ka_attn(
    const float* __restrict__ enc_proj, const float* __restrict__ enc,
    const float* __restrict__ q, const float* __restrict__ v,
    float* __restrict__ u_out, float* __restrict__ ctx_part,
    float* __restrict__ s_part)
{
    const int b     = blockIdx.x >> 4;
    const int chunk = blockIdx.x & 15;
    const int lane  = threadIdx.x;      // 0..63
    const int t0    = chunk * 64;

    __shared__ __align__(16) float qs[256];
    __shared__ __align__(16) float vs[256];
    __shared__ __align__(16) float el[64];

    ((float4*)qs)[lane] = ((const float4*)(q + b * 256))[lane];
    ((float4*)vs)[lane] = ((const float4*)v)[lane];
    __syncthreads();

    // ---- stage 1: lane owns row (t0 + lane), nt stream ----
    const float4* prow = (const float4*)(enc_proj + ((size_t)(b * T_ + t0 + lane)) * 256);
    const float4* qv4  = (const float4*)qs;
    const float4* vv4  = (const float4*)vs;

    float s0 = 0.f, s1 = 0.f, s2 = 0.f, s3 = 0.f;
    #pragma unroll
    for (int k = 0; k < 16; k += 4) {
        float4 p0 = nt_load4(&prow[k + 0]);
        float4 p1 = nt_load4(&prow[k + 1]);
        float4 p2 = nt_load4(&prow[k + 2]);
        float4 p3 = nt_load4(&prow[k + 3]);
        float4 q0 = qv4[k + 0],  q1 = qv4[k + 1],  q2 = qv4[k + 2],  q3 = qv4[k + 3];
        float4 v0 = vv4[k + 0],  v1 = vv4[k + 1],  v2 = vv4[k + 2],  v3 = vv4[k + 3];
        s0 += tanh_fast(p0.x + q0.x) * v0.x + tanh_fast(p0.y + q0.y) * v0.y
            + tanh_fast(p0.z + q0.z) * v0.z + tanh_fast(p0.w + q0.w) * v0.w;
        s1 += tanh_fast(p1.x + q1.x) * v1.x + tanh_fast(p1.y + q1.y) * v1.y
            + tanh_fast(p1.z + q1.z) * v1.z + tanh_fast(p1.w + q1.w) * v1.w;
        s2 += tanh_fast(p2.x + q2.x) * v2.x + tanh_fast(p2.y + q2.y) * v2.y
            + tanh_fast(p2.z + q2.z) * v2.z + tanh_fast(p2.w + q2.w) * v2.w;
        s3 += tanh_fast(p3.x + q3.x) * v3.x + tanh_fast(p3.y + q3.y) * v3.y
            + tanh_fast(p3.z + q3.z) * v3.z + tanh_fast(p3.w + q3.w) * v3.w;
    }
    float u = (s0 + s1) + (s2 + s3);
    u_out[b * T_ + t0 + lane] = u;                 // coalesced 256B store

    float e = __expf(u);
    el[lane] = e;
    float ssum = waveReduceSum(e);
    if (lane == 0) s_part[b * 16 + chunk] = ssum;
    __syncthreads();

    // ---- stage 3: stream 64 contiguous enc rows (nt) ----
    const float4* erow = (const float4*)(enc + ((size_t)(b * T_ + t0)) * 256);
    const float4* e4p  = (const float4*)el;
    float4 accA = {0.f, 0.f, 0.f, 0.f}, accB = {0.f, 0.f, 0.f, 0.f};

    #pragma unroll 4
    for (int t = 0; t < 64; t += 4) {
        float4 e4 = e4p[t >> 2];
        float4 r0 = nt_load4(&erow[(size_t)(t + 0) * 64 + lane]);
        float4 r1 = nt_load4(&erow[(size_t)(t + 1) * 64 + lane]);
        float4 r2 = nt_load4(&erow[(size_t)(t + 2) * 64 + lane]);
        float4 r3 = nt_load4(&erow[(size_t)(t + 3) * 64 + lane]);
        accA.x += e4.x * r0.x; accA.y += e4.x * r0.y; accA.z += e4.x * r0.z; accA.w += e4.x * r0.w;
        accB.x += e4.y * r1.x; accB.y += e4.y * r1.y; accB.z += e4.y * r1.z; accB.w += e4.y * r1.w;
        accA.x += e4.z * r2.x; accA.y += e4.z * r2.y; accA.z += e4.z * r2.z; accA.w += e4.z * r2.w;
        accB.x += e4.w * r3.x; accB.y += e4.w * r3.y; accB.z += e4.w * r3.z; accB.w += e4.w * r3.w;
    }
    accA.x += accB.x; accA.y += accB.y; accA.z += accB.z; accA.w += accB.w;
    ((float4*)ctx_part)[(size_t)(b * 16 + chunk) * 64 + lane] = accA;   // coalesced 1KB
}

// ---------------------------------------------------------------------------
// KB: combine 16 partials -> context, scores, concat1.  grid=128 (per batch)
// ---------------------------------------------------------------------------
__global__ __launch_bounds__(256) void kb_combine(
    const float* __restrict__ u, const float* __restrict__ s_part,
    const float* __restrict__ ctx_part, const float* __restrict__ attn_h,
    float* __restrict__ scores_out, float* __restrict__ ctx_out,
    float* __restrict__ concat1)
{
    const int b = blockIdx.x, tid = threadIdx.x;
    __shared__ float ssh[16];
    if (tid < 16) ssh[tid] = s_part[b * 16 + tid];
    __syncthreads();

    float S = 0.f;
    #pragma unroll
    for (int c = 0; c < 16; c++) S += ssh[c];
    float invS = 1.f / S;

    {
        float a = 0.f;
        #pragma unroll
        for (int c = 0; c < 16; c++)
            a += ctx_part[(size_t)(b * 16 + c) * 256 + tid];
        a *= invS;
        ctx_out[b * 256 + tid] = a;
        concat1[b * 512 + tid] = a;
        concat1[b * 512 + 256 + tid] = attn_h[b * 256 + tid];
    }

    #pragma unroll
    for (int i = 0; i < 4; i++) {
        int t = i * 256 + tid;
        scores_out[b * T_ + t] = __expf(u[b * T_ + t]) * invS;
    }
}

// ---------------------------------------------------------------------------
// GEMM: part[z][m][n] = A_seg[m][k0:k0+KSZ] @ W_seg[n][k0:k0+KSZ]^T
// ---------------------------------------------------------------------------
__global__ __launch_bounds__(256) void gemm512_splitk(
    const float* __restrict__ A1, const float* __restrict__ W1,
    const float* __restrict__ A2, const float* __restrict__ W2,
    float* __restrict__ part, int N, int ksPerSeg)
{
    const int n0 = blockIdx.x * 64, m0 = blockIdx.y * 64;
    const int seg = blockIdx.z / ksPerSeg, ls = blockIdx.z % ksPerSeg;
    const int KSZ = 512 / ksPerSeg;
    const float* A = seg ? A2 : A1;
    const float* W = seg ? W2 : W1;
    const int k0 = ls * KSZ;

    __shared__ __align__(16) float As[32][68];
    __shared__ __align__(16) float Ws[32][68];

    const int tid = threadIdx.x;
    const int tm = tid & 15, tn = tid >> 4;
    const int rs = tid >> 3, qs = tid & 7;

    float acc[4][4] = {};

    for (int kt = 0; kt < KSZ; kt += 32) {
        #pragma unroll
        for (int it = 0; it < 2; it++) {
            int r = rs + it * 32;
            float4 av = *(const float4*)(A + (size_t)(m0 + r) * 512 + k0 + kt + qs * 4);
            As[qs * 4 + 0][r] = av.x; As[qs * 4 + 1][r] = av.y;
            As[qs * 4 + 2][r] = av.z; As[qs * 4 + 3][r] = av.w;
            float4 wv = *(const float4*)(W + (size_t)(n0 + r) * 512 + k0 + kt + qs * 4);
            Ws[qs * 4 + 0][r] = wv.x; Ws[qs * 4 + 1][r] = wv.y;
            Ws[qs * 4 + 2][r] = wv.z; Ws[qs * 4 + 3][r] = wv.w;
        }
        __syncthreads();
        #pragma unroll
        for (int kk = 0; kk < 32; kk++) {
            float4 a = *(const float4*)&As[kk][tm * 4];
            float4 w = *(const float4*)&Ws[kk][tn * 4];
            acc[0][0] += a.x * w.x; acc[0][1] += a.x * w.y; acc[0][2] += a.x * w.z; acc[0][3] += a.x * w.w;
            acc[1][0] += a.y * w.x; acc[1][1] += a.y * w.y; acc[1][2] += a.y * w.z; acc[1][3] += a.y * w.w;
            acc[2][0] += a.z * w.x; acc[2][1] += a.z * w.y; acc[2][2] += a.z * w.z; acc[2][3] += a.z * w.w;
            acc[3][0] += a.w * w.x; acc[3][1] += a.w * w.y; acc[3][2] += a.w * w.z; acc[3][3] += a.w * w.w;
        }
        __syncthreads();
    }

    float* pb = part + ((size_t)blockIdx.z * 128 + m0) * N + n0;
    #pragma unroll
    for (int i = 0; i < 4; i++) {
        float4 o = {acc[i][0], acc[i][1], acc[i][2], acc[i][3]};
        *(float4*)(pb + (size_t)(tm * 4 + i) * N + tn * 4) = o;
    }
}

// ---------------------------------------------------------------------------
// E_rnn: x = sum_z part[z] + bias     (N=512, 16 slices)
// ---------------------------------------------------------------------------
__global__ __launch_bounds__(256) void e_rnn(
    const float* __restrict__ part, const float* __restrict__ bias,
    float* __restrict__ x)
{
    const int idx = blockIdx.x * 256 + threadIdx.x;
    const int n = idx & 511;
    float a = bias[n];
    #pragma unroll
    for (int z = 0; z < 16; z++) a += part[(size_t)z * 65536 + idx];
    x[idx] = a;
}

// ---------------------------------------------------------------------------
__global__ __launch_bounds__(256) void e_lstm(
    const float* __restrict__ part,
    const float* __restrict__ bih, const float* __restrict__ bhh,
    const float* __restrict__ c_prev, const float* __restrict__ x_prev,
    float* __restrict__ h_out, float* __restrict__ c_out, float* __restrict__ x_new)
{
    const int idx = blockIdx.x * 256 + threadIdx.x;
    const int bb = idx >> 9, j = idx & 511;
    float gi = bih[j] + bhh[j];
    float gf = bih[512 + j] + bhh[512 + j];
    float gg = bih[1024 + j] + bhh[1024 + j];
    float go = bih[1536 + j] + bhh[1536 + j];
    #pragma unroll
    for (int z = 0; z < 4; z++) {
        const float* p = part + ((size_t)z * 128 + bb) * 2048;
        gi += p[j]; gf += p[512 + j]; gg += p[1024 + j]; go += p[1536 + j];
    }
    float c = sigmoidf_(gf) * c_prev[idx] + sigmoidf_(gi) * tanhf_(gg);
    float h = sigmoidf_(go) * tanhf_(c);
    h_out[idx] = h;
    c_out[idx] = c;
    x_new[idx] = x_prev[idx] + h;
}

// ---------------------------------------------------------------------------
__global__ __launch_bounds__(512) void e_lstm2_mel(
    const float* __restrict__ part,
    const float* __restrict__ bih, const float* __restrict__ bhh,
    const float* __restrict__ c_prev, const float* __restrict__ x_prev,
    const float* __restrict__ mel_W, const int* __restrict__ r_ptr,
    float* __restrict__ h_out, float* __restrict__ c_out,
    float* __restrict__ mels)
{
    const int b = blockIdx.x, j = threadIdx.x;
    __shared__ __align__(16) float xs[512];

    const int idx = b * 512 + j;
    float gi = bih[j] + bhh[j];
    float gf = bih[512 + j] + bhh[512 + j];
    float gg = bih[1024 + j] + bhh[1024 + j];
    float go = bih[1536 + j] + bhh[1536 + j];
    #pragma unroll
    for (int z = 0; z < 4; z++) {
        const float* p = part + ((size_t)z * 128 + b) * 2048;
        gi += p[j]; gf += p[512 + j]; gg += p[1024 + j]; go += p[1536 + j];
    }
    float c = sigmoidf_(gf) * c_prev[idx] + sigmoidf_(gi) * tanhf_(gg);
    float h = sigmoidf_(go) * tanhf_(c);
    h_out[idx] = h;
    c_out[idx] = c;
    xs[j] = x_prev[idx] + h;
    __syncthreads();

    const int r = r_ptr[0];
    const int tot = 80 * r;
    for (int n = j; n < tot; n += 512) {
        int m = n / r, rr = n % r;
        const float4* w  = (const float4*)(mel_W + (size_t)(m * 20 + rr) * 512);
        const float4* xv = (const float4*)xs;
        float a = 0.f;
        #pragma unroll 8
        for (int k = 0; k < 128; k++) {
            float4 wv = w[k], vv = xv[k];
            a += wv.x * vv.x + wv.y * vv.y + wv.z * vv.z + wv.w * vv.w;
        }
        mels[(size_t)b * tot + n] = a;
    }
}

// ---------------------------------------------------------------------------
extern "C" void kernel_launch(void* const* d_in, const int* in_sizes, int n_in,
                              void* d_out, int out_size, void* d_ws, size_t ws_size,
                              hipStream_t stream)
{
    const float* enc   = (const float*)d_in[0];
    const float* encp  = (const float*)d_in[1];
    const float* pre   = (const float*)d_in[2];
    const float* ah_in = (const float*)d_in[3];
    const float* r1h   = (const float*)d_in[4];
    const float* r2h   = (const float*)d_in[5];
    const float* r1c   = (const float*)d_in[6];
    const float* r2c   = (const float*)d_in[7];
    const float* cvec  = (const float*)d_in[8];
    const float* fc1W  = (const float*)d_in[9];
    const float* fc1b  = (const float*)d_in[10];
    const float* fc2W  = (const float*)d_in[11];
    const float* fc2b  = (const float*)d_in[12];
    const float* attnW = (const float*)d_in[13];
    const float* attnv = (const float*)d_in[14];
    const float* gWih  = (const float*)d_in[15];
    const float* gWhh  = (const float*)d_in[16];
    const float* gbih  = (const float*)d_in[17];
    const float* gbhh  = (const float*)d_in[18];
    const float* rinW  = (const float*)d_in[19];
    const float* rinb  = (const float*)d_in[20];
    const float* l1Wih = (const float*)d_in[21];
    const float* l1Whh = (const float*)d_in[22];
    const float* l1bih = (const float*)d_in[23];
    const float* l1bhh = (const float*)d_in[24];
    const float* l2Wih = (const float*)d_in[25];
    const float* l2Whh = (const float*)d_in[26];
    const float* l2bih = (const float*)d_in[27];
    const float* l2bhh = (const float*)d_in[28];
    const float* melW  = (const float*)d_in[29];
    const int*   rp    = (const int*)d_in[30];

    float* out = (float*)d_out;
    float* o_mels  = out + 0;        // 128*80*2
    float* o_scor  = out + 20480;    // 128*1024
    float* o_attnh = out + 151552;   // 128*256
    float* o_r1h   = out + 184320;   // 128*512
    float* o_r2h   = out + 249856;
    float* o_r1c   = out + 315392;
    float* o_r2c   = out + 380928;
    float* o_ctx   = out + 446464;   // 128*256

    float* ws     = (float*)d_ws;
    float* w_q    = ws + 0;          // 32768
    float* w_u    = ws + 32768;      // 131072
    float* w_s    = ws + 163840;     // 2048
    float* w_ctxp = ws + 165888;     // 16*128*256 = 524288
    float* w_cat1 = ws + 692224;     // 65536
    float* w_x    = ws + 757760;     // 65536
    float* w_x2   = ws + 823296;     // 65536
    float* w_part = ws + 888832;     // 16*128*512 = 1048576 max

    // front-end scratch reuses the w_part region (free until the GEMM phase)
    float* w_p2 = w_part;            // 128*128
    float* w_gi = w_part + 16384;    // 128*768
    float* w_gh = w_part + 114688;   // 128*768

    hipLaunchKernelGGL(k1a_prenet, dim3(128), dim3(256), 0, stream,
                       pre, fc1W, fc1b, fc2W, fc2b, w_p2);

    hipLaunchKernelGGL(k1b_gru_gemv, dim3(3, 64), dim3(256), 0, stream,
                       cvec, w_p2, ah_in, gWih, gWhh, gbih, gbhh, w_gi, w_gh);

    hipLaunchKernelGGL(k1c_gates_q, dim3(128), dim3(256), 0, stream,
                       w_gi, w_gh, ah_in, attnW, o_attnh, w_q);

    hipLaunchKernelGGL(ka_attn, dim3(2048), dim3(64), 0, stream,
                       encp, enc, w_q, attnv, w_u, w_ctxp, w_s);

    hipLaunchKernelGGL(kb_combine, dim3(128), dim3(256), 0, stream,
                       w_u, w_s, w_ctxp, o_attnh, o_scor, o_ctx, w_cat1);

    // rnn_in: K=512, 16 k-slices -> 256 blocks
    hipLaunchKernelGGL(gemm512_splitk, dim3(8, 2, 16), dim3(256), 0, stream,
                       w_cat1, rinW, w_cat1, rinW, w_part, 512, 16);
    hipLaunchKernelGGL(e_rnn, dim3(256), dim3(256), 0, stream, w_part, rinb, w_x);

    // LSTM 1
    hipLaunchKernelGGL(gemm512_splitk, dim3(32, 2, 4), dim3(256), 0, stream,
                       w_x, l1Wih, r1h, l1Whh, w_part, 2048, 2);
    hipLaunchKernelGGL(e_lstm, dim3(256), dim3(256), 0, stream,
                       w_part, l1bih, l1bhh, r1c, w_x, o_r1h, o_r1c, w_x2);

    // LSTM 2 + mel
    hipLaunchKernelGGL(gemm512_splitk, dim3(32, 2, 4), dim3(256), 0, stream,
                       w_x2, l2Wih, r2h, l2Whh, w_part, 2048, 2);
    hipLaunchKernelGGL(e_lstm2_mel, dim3(128), dim3(512), 0, stream,
                       w_part, l2bih, l2bhh, r2c, w_x2, melW, rp,
                       o_r2h, o_r2c, o_mels);
}